// Round 11
// baseline (409.130 us; speedup 1.0000x reference)
//
#include <hip/hip_runtime.h>

// ---------------------------------------------------------------------------
// DeepConvWeigthNet on MI355X — round 6: in-block software pipelining.
//  vs round 5: conv1/conv2/conv3/head blocks process TY=4 y-subtiles with
//  async-STAGE split (issue tile t+1 global loads -> regs before compute(t);
//  vmcnt-wait + ds_write after the post-compute barrier). Weight A-frag
//  3-buffer rotation is seamless across tiles (prefetch (j+2)%9).
// Workspace ~134.3 MB: region0 body1 67.1 | region1 t64 67.1 | tail.
// ---------------------------------------------------------------------------

typedef __attribute__((ext_vector_type(8))) short short8v;
typedef __attribute__((ext_vector_type(4))) short short4v;
typedef __attribute__((ext_vector_type(4))) float f32x4;

__device__ inline short f2bf(float f) {
  unsigned u = __builtin_bit_cast(unsigned, f);
  unsigned r = (u + 0x7fffu + ((u >> 16) & 1u)) >> 16;
  return (short)r;
}

// Weight prep: fp32 -> bf16, per-lane MFMA A-frag layout (unchanged).
__global__ void prep_k(const float* __restrict__ w1, const float* __restrict__ w2,
                       const float* __restrict__ w3,
                       const float* __restrict__ hw0, const float* __restrict__ hw1,
                       const float* __restrict__ hw2,
                       const float* __restrict__ hb0, const float* __restrict__ hb1,
                       const float* __restrict__ hb2,
                       short* __restrict__ wt2, short* __restrict__ wt3,
                       short* __restrict__ wth, short* __restrict__ wtc1,
                       float* __restrict__ hbp)
{
  const int N0 = 18432, N1 = 18432, N2 = 4608, N3 = 9216;
  for (int idx = blockIdx.x * 256 + threadIdx.x; idx < N0 + N1 + N2 + N3 + 16;
       idx += gridDim.x * 256) {
    if (idx < N0) {                       // Wt2: [tap][mt4][lane][8]
      int t = idx, j = t & 7, l = (t >> 3) & 63, mt = (t >> 9) & 3, tap = t >> 11;
      int oc = mt * 16 + (l & 15), k = ((l >> 4) << 3) + j;
      wt2[t] = f2bf(w2[(oc * 32 + k) * 9 + tap]);
    } else if (idx < N0 + N1) {           // Wt3: [tap][mt2][kc2][lane][8]
      int t = idx - N0, j = t & 7, l = (t >> 3) & 63, kc = (t >> 9) & 1,
          mt = (t >> 10) & 1, tap = t >> 11;
      int oc = mt * 16 + (l & 15), ic = kc * 32 + ((l >> 4) << 3) + j;
      wt3[t] = f2bf(w3[(oc * 64 + ic) * 9 + tap]);
    } else if (idx < N0 + N1 + N2) {      // WtH: [tap][lane][8], oc15 = 0
      int t = idx - N0 - N1, j = t & 7, l = (t >> 3) & 63, tap = t >> 9;
      int oc = l & 15, ic = ((l >> 4) << 3) + j;
      float v = 0.f;
      if (oc < 15) {
        const float* hw = (oc < 5) ? hw0 : (oc < 10) ? hw1 : hw2;
        v = hw[((oc % 5) * 32 + ic) * 9 + tap];
      }
      wth[t] = f2bf(v);
    } else if (idx < N0 + N1 + N2 + N3) { // WtC1: [tap][mt2][lane][8], k>=3 = 0
      int t = idx - N0 - N1 - N2, j = t & 7, l = (t >> 3) & 63,
          mt = (t >> 9) & 1, tap = t >> 10;
      int oc = mt * 16 + (l & 15), k = ((l >> 4) << 3) + j;
      wtc1[t] = f2bf((k < 3) ? w1[(oc * 3 + k) * 9 + tap] : 0.f);
    } else {                              // hbp[16]
      int oc = idx - N0 - N1 - N2 - N3;
      float v = 0.f;
      if (oc < 15) v = ((oc < 5) ? hb0 : (oc < 10) ? hb1 : hb2)[oc % 5];
      hbp[oc] = v;
    }
  }
}

// conv1: 3->32, fp32 planar -> bf16 ic-minor. TY=4 pipelined y-subtiles.
__global__ __launch_bounds__(256)
void conv1_k(const float* __restrict__ x, const short* __restrict__ wt,
             const float* __restrict__ bias, const float* __restrict__ alpha_p,
             short* __restrict__ outb, int H, int W)
{
  constexpr int TY = 4;
  __shared__ short tile[340 * 4];
  const int tid = threadIdx.x, lane = tid & 63;
  const int x0 = blockIdx.x * 32, yb0 = blockIdx.y * 8 * TY, b = blockIdx.z;
  const size_t HW = (size_t)H * W;
  const float* xb = x + (size_t)b * 3 * HW;

  short8v A[9][2];
#pragma unroll
  for (int t = 0; t < 9; ++t) {
    A[t][0] = *(const short8v*)(wt + (((t * 2 + 0) * 64) + lane) * 8);
    A[t][1] = *(const short8v*)(wt + (((t * 2 + 1) * 64) + lane) * 8);
  }

  const int wid = tid >> 6, g = (tid >> 4) & 3, n = tid & 15;
  const float alpha = alpha_p[0];
  float bv[2][4];
#pragma unroll
  for (int mt = 0; mt < 2; ++mt)
#pragma unroll
    for (int r = 0; r < 4; ++r) bv[mt][r] = bias[mt * 16 + g * 4 + r];
  short* ob = outb + (size_t)b * HW * 32;

  float f0[2], f1[2], f2[2];
  // prologue: load tile 0
#pragma unroll
  for (int i = 0; i < 2; ++i) {
    int px = tid + i * 256;
    f0[i] = f1[i] = f2[i] = 0.f;
    if (px < 340) {
      int row = px / 34, col = px - row * 34;
      int gy = yb0 - 1 + row, gx = x0 - 1 + col;
      if ((unsigned)gy < (unsigned)H && (unsigned)gx < (unsigned)W) {
        size_t o = (size_t)gy * W + gx;
        f0[i] = xb[o]; f1[i] = xb[HW + o]; f2[i] = xb[2 * HW + o];
      }
    }
  }
#pragma unroll
  for (int i = 0; i < 2; ++i) {
    int px = tid + i * 256;
    if (px < 340) {
      short4v v = {f2bf(f0[i]), f2bf(f1[i]), f2bf(f2[i]), 0};
      *(short4v*)&tile[px * 4] = v;
    }
  }
  __syncthreads();

#pragma unroll
  for (int t = 0; t < TY; ++t) {
    const int yt0 = yb0 + t * 8;
    if (t + 1 < TY) {
#pragma unroll
      for (int i = 0; i < 2; ++i) {
        int px = tid + i * 256;
        f0[i] = f1[i] = f2[i] = 0.f;
        if (px < 340) {
          int row = px / 34, col = px - row * 34;
          int gy = yt0 + 7 + row, gx = x0 - 1 + col;   // (yt0+8)-1+row
          if ((unsigned)gy < (unsigned)H && (unsigned)gx < (unsigned)W) {
            size_t o = (size_t)gy * W + gx;
            f0[i] = xb[o]; f1[i] = xb[HW + o]; f2[i] = xb[2 * HW + o];
          }
        }
      }
    }

    f32x4 acc[2][4];
#pragma unroll
    for (int m = 0; m < 2; ++m)
#pragma unroll
      for (int q = 0; q < 4; ++q) acc[m][q] = (f32x4){0.f, 0.f, 0.f, 0.f};
#pragma unroll
    for (int tap = 0; tap < 9; ++tap) {
      const int dy = tap / 3 - 1, dx = tap % 3 - 1;
#pragma unroll
      for (int nt = 0; nt < 4; ++nt) {
        const int row_l = 1 + 2 * wid + (nt >> 1) + dy;
        const int col_l = 1 + ((nt & 1) << 4) + dx + n;
        short4v s = *(const short4v*)&tile[(row_l * 34 + col_l) * 4];
        short8v B = {0, 0, 0, 0, 0, 0, 0, 0};
        if (g == 0) { B[0] = s[0]; B[1] = s[1]; B[2] = s[2]; }
        acc[0][nt] = __builtin_amdgcn_mfma_f32_16x16x32_bf16(A[tap][0], B, acc[0][nt], 0, 0, 0);
        acc[1][nt] = __builtin_amdgcn_mfma_f32_16x16x32_bf16(A[tap][1], B, acc[1][nt], 0, 0, 0);
      }
    }
#pragma unroll
    for (int nt = 0; nt < 4; ++nt) {
      const int py = yt0 + 2 * wid + (nt >> 1), px = x0 + ((nt & 1) << 4) + n;
#pragma unroll
      for (int mt = 0; mt < 2; ++mt) {
        short4v o4;
#pragma unroll
        for (int r = 0; r < 4; ++r) {
          float v = acc[mt][nt][r] + bv[mt][r];
          v = v > 0.f ? v : alpha * v;
          o4[r] = f2bf(v);
        }
        *(short4v*)(ob + ((size_t)(py * W + px) * 32 + mt * 16 + g * 4)) = o4;
      }
    }
    if (t + 1 < TY) {
      __syncthreads();
#pragma unroll
      for (int i = 0; i < 2; ++i) {
        int px = tid + i * 256;
        if (px < 340) {
          short4v v = {f2bf(f0[i]), f2bf(f1[i]), f2bf(f2[i]), 0};
          *(short4v*)&tile[px * 4] = v;
        }
      }
      __syncthreads();
    }
  }
}

// 3x3 conv as 9 shifted GEMMs; TY pipelined y-subtiles, async-STAGE split.
template<int KC, int MT, int CPAD, bool PRELU, bool HEAD, int TY>
__global__ __launch_bounds__(256)
void mconv_k(const short* __restrict__ in, const short* __restrict__ wt,
             const float* __restrict__ bias, const float* __restrict__ alpha_p,
             short* __restrict__ outb, float* __restrict__ outy,
             float* __restrict__ part, int H, int W)
{
  constexpr int CIN = KC * 32, NCH = KC * 4, CMASK = NCH - 1;
  constexpr int NFRAG = MT * KC;
  constexpr int NLOAD = 340 * NCH;
  constexpr int LP = (NLOAD + 255) / 256;
  __shared__ short tile[10 * 34 * CPAD];
  __shared__ float hsum[16];
  const int tid = threadIdx.x, lane = tid & 63;
  if (HEAD && tid < 16) hsum[tid] = 0.f;
  const int x0 = blockIdx.x * 32, yb0 = blockIdx.y * 8 * TY, b = blockIdx.z;
  const size_t HW = (size_t)H * W;
  const short* inb = in + (size_t)b * HW * CIN;

  // weight taps 0,1 into rotation buffers 0,1 (weights are tile-invariant)
  short8v A[3][NFRAG];
#pragma unroll
  for (int f = 0; f < NFRAG; ++f)
    A[0][f] = *(const short8v*)(wt + ((size_t)f * 64 + lane) * 8);
#pragma unroll
  for (int f = 0; f < NFRAG; ++f)
    A[1][f] = *(const short8v*)(wt + ((size_t)(NFRAG + f) * 64 + lane) * 8);

  const int wid = tid >> 6, g = (tid >> 4) & 3, n = tid & 15;

  short8v rv[LP];
  // prologue: load + write tile 0
#pragma unroll
  for (int i = 0; i < LP; ++i) {
    int idx = tid + i * 256;
    short8v v = {0, 0, 0, 0, 0, 0, 0, 0};
    if (idx < NLOAD) {
      int q = idx & CMASK, px = idx / NCH;
      int row = px / 34, col = px - row * 34;
      int gy = yb0 - 1 + row, gx = x0 - 1 + col;
      if ((unsigned)gy < (unsigned)H && (unsigned)gx < (unsigned)W)
        v = *(const short8v*)(inb + ((size_t)(gy * W + gx) * CIN + q * 8));
    }
    rv[i] = v;
  }
#pragma unroll
  for (int i = 0; i < LP; ++i) {
    int idx = tid + i * 256;
    if (idx < NLOAD) {
      int q = idx & CMASK, px = idx / NCH;
      int col = px - (px / 34) * 34;
      *(short8v*)&tile[px * CPAD + (q ^ (col & CMASK)) * 8] = rv[i];
    }
  }
  __syncthreads();

#pragma unroll 1
  for (int t = 0; t < TY; ++t) {
    const int yt0 = yb0 + t * 8;
    if (t + 1 < TY) {
#pragma unroll
      for (int i = 0; i < LP; ++i) {
        int idx = tid + i * 256;
        short8v v = {0, 0, 0, 0, 0, 0, 0, 0};
        if (idx < NLOAD) {
          int q = idx & CMASK, px = idx / NCH;
          int row = px / 34, col = px - row * 34;
          int gy = yt0 + 7 + row, gx = x0 - 1 + col;
          if ((unsigned)gy < (unsigned)H && (unsigned)gx < (unsigned)W)
            v = *(const short8v*)(inb + ((size_t)(gy * W + gx) * CIN + q * 8));
        }
        rv[i] = v;
      }
    }

    f32x4 acc[MT][4];
#pragma unroll
    for (int m = 0; m < MT; ++m)
#pragma unroll
      for (int q = 0; q < 4; ++q) acc[m][q] = (f32x4){0.f, 0.f, 0.f, 0.f};

#pragma unroll
    for (int j = 0; j < 9; ++j) {
      // prefetch weights for tap (j+2)%9 into buffer (j+2)%3 (seamless wrap)
#pragma unroll
      for (int f = 0; f < NFRAG; ++f)
        A[(j + 2) % 3][f] = *(const short8v*)(
            wt + ((size_t)(((j + 2) % 9) * NFRAG + f) * 64 + lane) * 8);
      const int dy = j / 3 - 1, dx = j % 3 - 1;
#pragma unroll
      for (int nt = 0; nt < 4; ++nt) {
        const int row_l = 1 + 2 * wid + (nt >> 1) + dy;
        const int col_l = 1 + ((nt & 1) << 4) + dx + n;
        const int base = (row_l * 34 + col_l) * CPAD;
        const int cm = col_l & CMASK;
#pragma unroll
        for (int kc = 0; kc < KC; ++kc) {
          const int slot = (kc * 4 + g) ^ cm;
          short8v B = *(const short8v*)&tile[base + slot * 8];
#pragma unroll
          for (int mt = 0; mt < MT; ++mt)
            acc[mt][nt] = __builtin_amdgcn_mfma_f32_16x16x32_bf16(
                A[j % 3][mt * KC + kc], B, acc[mt][nt], 0, 0, 0);
        }
      }
    }

    if constexpr (!HEAD) {
      const float alpha = PRELU ? alpha_p[0] : 0.f;
      float bv[MT][4];
#pragma unroll
      for (int mt = 0; mt < MT; ++mt)
#pragma unroll
        for (int r = 0; r < 4; ++r) bv[mt][r] = bias[mt * 16 + g * 4 + r];
      short* ob = outb + (size_t)b * HW * (MT * 16);
#pragma unroll
      for (int nt = 0; nt < 4; ++nt) {
        const int py = yt0 + 2 * wid + (nt >> 1), px = x0 + ((nt & 1) << 4) + n;
#pragma unroll
        for (int mt = 0; mt < MT; ++mt) {
          short4v o4;
#pragma unroll
          for (int r = 0; r < 4; ++r) {
            float v = acc[mt][nt][r] + bv[mt][r];
            if (PRELU) v = v > 0.f ? v : alpha * v;
            o4[r] = f2bf(v);
          }
          *(short4v*)(ob + ((size_t)(py * W + px) * (MT * 16) + mt * 16 + g * 4)) = o4;
        }
      }
    } else {
      float bv[4];
#pragma unroll
      for (int r = 0; r < 4; ++r) bv[r] = bias[g * 4 + r];
      float ps[4] = {0.f, 0.f, 0.f, 0.f};
#pragma unroll
      for (int nt = 0; nt < 4; ++nt) {
        const int py = yt0 + 2 * wid + (nt >> 1), px = x0 + ((nt & 1) << 4) + n;
#pragma unroll
        for (int r = 0; r < 4; ++r) {
          const int oc = g * 4 + r;
          float v = acc[0][nt][r] + bv[r];
          if (oc < 15) outy[(size_t)(b * 15 + oc) * HW + (size_t)py * W + px] = v;
          ps[r] += v;
        }
      }
#pragma unroll
      for (int r = 0; r < 4; ++r) {
        float s = ps[r];
#pragma unroll
        for (int m = 1; m < 16; m <<= 1) s += __shfl_xor(s, m, 16);
        if (n == 0 && (g * 4 + r) < 15) atomicAdd(&hsum[g * 4 + r], s);  // LDS
      }
    }

    if (t + 1 < TY) {
      __syncthreads();
#pragma unroll
      for (int i = 0; i < LP; ++i) {
        int idx = tid + i * 256;
        if (idx < NLOAD) {
          int q = idx & CMASK, px = idx / NCH;
          int col = px - (px / 34) * 34;
          *(short8v*)&tile[px * CPAD + (q ^ (col & CMASK)) * 8] = rv[i];
        }
      }
      __syncthreads();
    }
  }

  if constexpr (HEAD) {
    __syncthreads();
    if (tid < 15)
      part[(size_t)(b * 15 + tid) * 256 + (blockIdx.y * 16 + blockIdx.x)] = hsum[tid];
  }
}

// Reduce per-block partials (256/[b,head,oc]) -> mean -> z.
__global__ __launch_bounds__(256)
void head_z_k(const float* __restrict__ part,
              const float* __restrict__ c1a, const float* __restrict__ c2a,
              const float* __restrict__ c1b, const float* __restrict__ c2b,
              const float* __restrict__ c1c, const float* __restrict__ c2c,
              float* __restrict__ z, float invHW)
{
  __shared__ float red[4];
  __shared__ float mm[5];
  const int tid = threadIdx.x;
  const int b = blockIdx.x / 3, h = blockIdx.x % 3;

#pragma unroll 1
  for (int oc = 0; oc < 5; ++oc) {
    const float* p = part + (size_t)(b * 15 + h * 5 + oc) * 256;
    float s = p[tid];
#pragma unroll
    for (int m = 1; m < 64; m <<= 1) s += __shfl_xor(s, m, 64);
    if ((tid & 63) == 0) red[tid >> 6] = s;
    __syncthreads();
    if (tid == 0) mm[oc] = (red[0] + red[1] + red[2] + red[3]) * invHW;
    __syncthreads();
  }

  if (tid == 0) {
    const float* w1 = (h == 0) ? c1a : (h == 1) ? c1b : c1c;
    const float* w2 = (h == 0) ? c2a : (h == 1) ? c2b : c2c;
    float tt[5];
#pragma unroll
    for (int o = 0; o < 5; ++o) {
      float s = 0.f;
#pragma unroll
      for (int i = 0; i < 5; ++i) s = fmaf(w1[o * 5 + i], mm[i], s);
      tt[o] = (s > 0.f) ? s : 0.f;
    }
#pragma unroll
    for (int o = 0; o < 5; ++o) {
      float s = 0.f;
#pragma unroll
      for (int i = 0; i < 5; ++i) s = fmaf(w2[o * 5 + i], tt[i], s);
      z[b * 15 + h * 5 + o] = 1.f / (1.f + expf(-s));
    }
  }
}

// Fully fused stage (unchanged, verified).
__global__ __launch_bounds__(256)
void stage_k(const float* __restrict__ xs, const float* __restrict__ y,
             const float* __restrict__ z, float* __restrict__ out,
             int hI, int H, int W)
{
  __shared__ float sx[56][56];
  __shared__ float sh5[56][32], sh15[56][32], sh25[56][32];

  const int tid = threadIdx.x;
  const int tx = tid & 31, tyg = tid >> 5;
  const int b = blockIdx.z;
  const int x0 = blockIdx.x * 32, y0 = blockIdx.y * 32;
  const size_t HW = (size_t)H * W;

  const float z0 = z[b * 15 + hI * 5 + 0], z1 = z[b * 15 + hI * 5 + 1],
              z2 = z[b * 15 + hI * 5 + 2], z3 = z[b * 15 + hI * 5 + 3],
              z4 = z[b * 15 + hI * 5 + 4];
  const float* yb_ = y + (size_t)(b * 15 + hI * 5) * HW;
  float hwt[4][5];
#pragma unroll
  for (int p = 0; p < 4; ++p) {
    const size_t pix = (size_t)(y0 + tyg * 4 + p) * W + (x0 + tx);
    float sv[5];
    sv[0] = yb_[0 * HW + pix] * z0;
    sv[1] = yb_[1 * HW + pix] * z1;
    sv[2] = yb_[2 * HW + pix] * z2;
    sv[3] = yb_[3 * HW + pix] * z3;
    sv[4] = yb_[4 * HW + pix] * z4;
    float mx = fmaxf(fmaxf(fmaxf(sv[0], sv[1]), fmaxf(sv[2], sv[3])), sv[4]);
    float se = 0.f;
#pragma unroll
    for (int c = 0; c < 5; ++c) { sv[c] = __expf(sv[c] - mx); se += sv[c]; }
    const float inv = 1.f / se;
#pragma unroll
    for (int c = 0; c < 5; ++c) hwt[p][c] = sv[c] * inv;
  }

#pragma unroll 1
  for (int ch = 0; ch < 3; ++ch) {
    const size_t plane = (size_t)(b * 3 + ch) * HW;
    const float* xp = xs + plane;
    __syncthreads();
    for (int t = tid; t < 56 * 56; t += 256) {
      int r = t / 56, c = t - r * 56;
      int gy = y0 + r - 12, gx = x0 + c - 12;
      sx[r][c] = ((unsigned)gy < (unsigned)H && (unsigned)gx < (unsigned)W)
                 ? xp[(size_t)gy * W + gx] : 0.f;
    }
    __syncthreads();
    for (int t = tid; t < 56 * 32; t += 256) {
      int r = t >> 5, j = t & 31;
      float s5 = 0.f;
#pragma unroll
      for (int d = -2; d <= 2; ++d) s5 += sx[r][j + 12 + d];
      float s15 = s5;
#pragma unroll
      for (int d = 3; d <= 7; ++d) s15 += sx[r][j + 12 + d] + sx[r][j + 12 - d];
      float s25 = s15;
#pragma unroll
      for (int d = 8; d <= 12; ++d) s25 += sx[r][j + 12 + d] + sx[r][j + 12 - d];
      sh5[r][j] = s5; sh15[r][j] = s15; sh25[r][j] = s25;
    }
    __syncthreads();
    const int hb = 12 + tyg * 4;
    float v5 = 0.f, v15 = 0.f, v25 = 0.f;
#pragma unroll
    for (int d = -2; d <= 2; ++d) v5 += sh5[hb + d][tx];
#pragma unroll
    for (int d = -7; d <= 7; ++d) v15 += sh15[hb + d][tx];
#pragma unroll
    for (int d = -12; d <= 12; ++d) v25 += sh25[hb + d][tx];
#pragma unroll
    for (int p = 0; p < 4; ++p) {
      const int yo = tyg * 4 + p;
      const float ctr = sx[12 + yo][12 + tx];
      const float sharp = 5.f * ctr - sx[11 + yo][12 + tx] - sx[13 + yo][12 + tx]
                                    - sx[12 + yo][11 + tx] - sx[12 + yo][13 + tx];
      const float res = hwt[p][0] * sharp
                      + hwt[p][1] * ctr
                      + hwt[p][2] * (v5  * (1.f / 25.f))
                      + hwt[p][3] * (v15 * (1.f / 225.f))
                      + hwt[p][4] * (v25 * (1.f / 625.f));
      out[plane + (size_t)(y0 + yo) * W + (x0 + tx)] = res;
      if (p < 3) {
        v5  += sh5 [hb + p + 3][tx] - sh5 [hb + p - 2][tx];
        v15 += sh15[hb + p + 8][tx] - sh15[hb + p - 7][tx];
        v25 += sh25[hb + p + 13][tx] - sh25[hb + p - 12][tx];
      }
    }
  }
}

extern "C" void kernel_launch(void* const* d_in, const int* in_sizes, int n_in,
                              void* d_out, int out_size, void* d_ws, size_t ws_size,
                              hipStream_t stream)
{
  const float* x   = (const float*)d_in[0];
  const float* w1  = (const float*)d_in[1];
  const float* b1  = (const float*)d_in[2];
  const float* a1  = (const float*)d_in[3];
  const float* w2  = (const float*)d_in[4];
  const float* b2  = (const float*)d_in[5];
  const float* a2  = (const float*)d_in[6];
  const float* w3  = (const float*)d_in[7];
  const float* b3  = (const float*)d_in[8];
  const float* a3  = (const float*)d_in[9];
  const float* hw[3]  = {(const float*)d_in[10], (const float*)d_in[14], (const float*)d_in[18]};
  const float* hb[3]  = {(const float*)d_in[11], (const float*)d_in[15], (const float*)d_in[19]};
  const float* cw1[3] = {(const float*)d_in[12], (const float*)d_in[16], (const float*)d_in[20]};
  const float* cw2[3] = {(const float*)d_in[13], (const float*)d_in[17], (const float*)d_in[21]};
  float* outp = (float*)d_out;

  const int B = 4, H = 512, W = 512;
  const size_t HW = (size_t)H * W;

  // Workspace (~134.3 MB):
  //   region0 [0, 67.1MB):    body1 bf16 [b][pix][32] (conv1 out; conv3 out;
  //                           after head: ping @0, pong @16MB)
  //   region1 [67.1,134.2MB): t64 bf16 2-batch [pix][64] (conv2 half-out;
  //                           after conv3: y planar fp32 60MB)
  //   tail   [134.2MB, ..):   Wt2|Wt3|WtH|WtC1|hbp|z|part
  char* ws = (char*)d_ws;
  short* body1 = (short*)ws;
  float* ping  = (float*)ws;
  float* pong  = (float*)(ws + 16777216);
  short* t64   = (short*)(ws + 67108864);
  float* ybuf  = (float*)(ws + 67108864);
  char* tail   = ws + 134217728;
  short* wt2   = (short*)tail;
  short* wt3   = wt2 + 18432;
  short* wth   = wt3 + 18432;
  short* wtc1  = wth + 4608;
  float* hbp   = (float*)(wtc1 + 9216);
  float* zbuf  = hbp + 16;
  float* part  = zbuf + 64;          // 60 * 256 floats = 61 KB

  prep_k<<<32, 256, 0, stream>>>(w1, w2, w3, hw[0], hw[1], hw[2],
                                 hb[0], hb[1], hb[2], wt2, wt3, wth, wtc1, hbp);

  // conv1: 3->32 + PReLU, TY=4 pipelined, one dispatch
  conv1_k<<<dim3(16, 16, B), 256, 0, stream>>>(x, wtc1, b1, a1, body1, H, W);

  // conv2 (32->64) / conv3 (64->32): two half-batch dispatches each, TY=4
  for (int h = 0; h < 2; ++h) {
    mconv_k<1, 4, 36, true, false, 4><<<dim3(16, 16, 2), 256, 0, stream>>>(
        body1 + (size_t)h * 2 * HW * 32, wt2, b2, a2, t64, nullptr, nullptr, H, W);
    mconv_k<2, 2, 68, true, false, 4><<<dim3(16, 16, 2), 256, 0, stream>>>(
        t64, wt3, b3, a3, body1 + (size_t)h * 2 * HW * 32, nullptr, nullptr, H, W);
  }

  // fused head conv (3 heads, 15 ocs) -> y planes (alias region1) + partials
  mconv_k<1, 1, 36, false, true, 4><<<dim3(16, 16, B), 256, 0, stream>>>(
      body1, wth, hbp, nullptr, nullptr, ybuf, part, H, W);

  const float invHW = 1.f / (float)(H * W);
  head_z_k<<<12, 256, 0, stream>>>(part, cw1[0], cw2[0], cw1[1], cw2[1],
                                   cw1[2], cw2[2], zbuf, invHW);

  // 3 fused stages (ping/pong alias body1, dead after head)
  const float* sin_[3]  = {x, ping, pong};
  float*       sout_[3] = {ping, pong, outp};
  for (int hI = 0; hI < 3; ++hI) {
    stage_k<<<dim3(16, 16, B), 256, 0, stream>>>(
        sin_[hI], ybuf, zbuf, sout_[hI], hI, H, W);
  }
}